// Round 5
// baseline (561.802 us; speedup 1.0000x reference)
//
#include <hip/hip_runtime.h>

// BiMamba. R5: counted-vmcnt 8-phase GEMM (T3+T4) for in-proj.
//  - All 4 stage_half calls for tile t+1 issue at TOP of tile t (T14
//    issue-early), then s_waitcnt vmcnt(8): tile t's 8 loads (issued one
//    full tile earlier) must land; t+1's 8 stay in flight across the tile.
//  - WAR-safe: buf[cur^1] reads (tile t-1) drained by per-phase lgkmcnt(0)
//    + phase-end barrier before the issue point.
// Everything else unchanged from R4.

#define Bsz  4
#define LSEQ 2048
#define DM   1024
#define DI   2048
#define DS   16
#define MROWS (Bsz * LSEQ) // 8192
#define NCH  32
#define CLEN 64

typedef unsigned short u16b;
typedef __attribute__((ext_vector_type(8))) short short8;
typedef __attribute__((ext_vector_type(4))) float f32x4;
typedef __attribute__((address_space(3))) unsigned int lds_u32;
typedef const __attribute__((address_space(1))) unsigned int glb_u32;

__device__ __forceinline__ float b2f(u16b u) {
  union { unsigned int i; float f; } x; x.i = ((unsigned int)u) << 16; return x.f;
}
__device__ __forceinline__ u16b f2b(float f) {
  union { float f; unsigned int i; } x; x.f = f;
  unsigned int r = x.i + 0x7FFFu + ((x.i >> 16) & 1u);
  return (u16b)(r >> 16);
}
__device__ __forceinline__ u16b f2b_cvt(float f) {
  unsigned int r;
  asm("v_cvt_pk_bf16_f32 %0, %1, %1" : "=v"(r) : "v"(f));
  return (u16b)r;
}
__device__ __forceinline__ float fast_rcp(float x) {
  return __builtin_amdgcn_rcpf(x);
}
__device__ __forceinline__ float softplus_fast(float v) {
  float e = __expf(-fabsf(v));
  return fmaxf(v, 0.f) + __logf(1.f + e);
}
__device__ __forceinline__ void pow_ladder(float q, float* dA) {
  float q2 = q * q, q3 = q2 * q, q4 = q2 * q2;
  float q5 = q4 * q, q6 = q4 * q2, q7 = q4 * q3, q8 = q4 * q4;
  dA[0] = q;  dA[1] = q2;  dA[2] = q3;  dA[3] = q4;
  dA[4] = q5; dA[5] = q6;  dA[6] = q7;  dA[7] = q8;
  dA[8] = q8 * q;  dA[9] = q8 * q2;  dA[10] = q8 * q3;  dA[11] = q8 * q4;
  dA[12] = q8 * q5; dA[13] = q8 * q6; dA[14] = q8 * q7; dA[15] = q8 * q8;
}

// Bijective XCD-aware block swizzle (requires nwg % 8 == 0; all our grids are).
__device__ __forceinline__ int xcd_swz(int id, int nwg) {
  int c = nwg >> 3;
  return (id & 7) * c + (id >> 3);
}

// ---- m97-style tile stage: 128 rows x 64 cols bf16, XOR-swizzled ----------
__device__ __forceinline__ void stage_tile(const u16b* gbase, int ld,
                                           u16b* lds, int wave, int lane) {
#pragma unroll
  for (int t = 0; t < 4; ++t) {
    int rb = wave * 32 + t * 8;
    int r = rb + (lane >> 3);
    int cb = (lane & 7) ^ (r & 7);
    const u16b* g = gbase + (size_t)r * ld + cb * 8;
    __builtin_amdgcn_global_load_lds((glb_u32*)g, (lds_u32*)(lds + rb * 64),
                                     16, 0, 0);
  }
}

// ---- 8-phase stage: one half-tile (128 rows x 64 cols), 512 threads -------
__device__ __forceinline__ void stage_half(const u16b* gbase, int ld,
                                           u16b* ldsbase, int tid) {
#pragma unroll
  for (int i2 = 0; i2 < 2; ++i2) {
    int rg = (tid >> 6) * 2 + i2;        // row-group of 8 rows, wave-uniform
    int row = rg * 8 + ((tid >> 3) & 7); // 0..127
    int cb = (tid & 7) ^ (row & 7);
    const u16b* g = gbase + (size_t)row * ld + cb * 8;
    __builtin_amdgcn_global_load_lds((glb_u32*)g,
                                     (lds_u32*)(ldsbase + rg * 8 * 64), 16, 0, 0);
  }
}

// ---------------- dtype sniffer -------------------------------------------
__global__ void sniff_kernel(const unsigned int* __restrict__ p,
                             int* __restrict__ flag) {
  unsigned int w = p[threadIdx.x];
  int e = (w >> 7) & 0xFF;
  unsigned long long m = __ballot(e >= 110 && e <= 135);
  if (threadIdx.x == 0) *flag = (__popcll(m) >= 32) ? 1 : 0;
}

// ---------------- input canonicalizer (-> bf16), big buffers ---------------
__global__ __launch_bounds__(256) void convert_kernel(
    const void* __restrict__ src, u16b* __restrict__ dst, int n,
    const int* __restrict__ flag) {
  int i = (blockIdx.x * 256 + threadIdx.x) * 8;
  if (i >= n) return;
  if (*flag) {
    *(uint4*)(dst + i) = *(const uint4*)((const u16b*)src + i);
  } else {
    const float* s = (const float*)src;
    float4 a = *(const float4*)(s + i);
    float4 b = *(const float4*)(s + i + 4);
    u16b o[8] = {f2b(a.x), f2b(a.y), f2b(a.z), f2b(a.w),
                 f2b(b.x), f2b(b.y), f2b(b.z), f2b(b.w)};
    *(uint4*)(dst + i) = *(uint4*)o;
  }
}

// ---------------- merged small converters ---------------------------------
struct SmallTab { const void* s[14]; u16b* d[14]; };
__global__ __launch_bounds__(256) void convert_small_kernel(
    SmallTab t, const int* __restrict__ flag) {
  const int pref[15] = {0,4,5,9,10,106,170,171,267,331,332,348,364,365,366};
  int bx = blockIdx.x;
  int seg = 0;
#pragma unroll
  for (int i = 0; i < 14; ++i)
    if (bx >= pref[i + 1]) seg = i + 1;
  int idx = (bx - pref[seg]) * 2048 + threadIdx.x * 8;
  u16b* dst = t.d[seg];
  if (*flag) {
    *(uint4*)(dst + idx) = *(const uint4*)((const u16b*)t.s[seg] + idx);
  } else {
    const float* s = (const float*)t.s[seg];
    float4 a = *(const float4*)(s + idx);
    float4 b = *(const float4*)(s + idx + 4);
    u16b o[8] = {f2b(a.x), f2b(a.y), f2b(a.z), f2b(a.w),
                 f2b(b.x), f2b(b.y), f2b(b.z), f2b(b.w)};
    *(uint4*)(dst + idx) = *(uint4*)o;
  }
}

// ---------------- 256^2 counted-vmcnt 8-phase bf16 NT GEMM (in-proj) -------
__global__ __launch_bounds__(512, 2) void gemm8_kernel(
    const u16b* __restrict__ A, const u16b* __restrict__ B,
    u16b* __restrict__ C, int M, int N, int K, int lda, int ldb, int ldc) {
  __shared__ u16b As[2][256 * 64];
  __shared__ u16b Bs[2][256 * 64];
  const int tid = threadIdx.x;
  const int nbx = gridDim.x;
  const int id = xcd_swz(blockIdx.y * nbx + blockIdx.x, nbx * gridDim.y);
  const int n0 = (id % nbx) * 256;
  const int m0 = (id / nbx) * 256;
  const int wave = tid >> 6, lane = tid & 63;
  const int wm = (wave >> 2) * 128, wn = (wave & 3) * 64;
  const int lr = lane & 15, lg = lane >> 4;

  const u16b* Ab = A + (size_t)m0 * lda;
  const u16b* Bb = B + (size_t)n0 * ldb;
  const int nt = K >> 6;

  f32x4 acc[8][4] = {};

  // prologue: tile 0 -> buf0 (no wait; the loop's counted wait covers it)
  stage_half(Ab, lda, As[0], tid);
  stage_half(Ab + (size_t)128 * lda, lda, As[0] + 8192, tid);
  stage_half(Bb, ldb, Bs[0], tid);
  stage_half(Bb + (size_t)128 * ldb, ldb, Bs[0] + 8192, tid);

  for (int t = 0; t < nt; ++t) {
    const int cur = t & 1;
    const u16b* Ac = As[cur];
    const u16b* Bc = Bs[cur];
    u16b* An = As[cur ^ 1];
    u16b* Bn = Bs[cur ^ 1];
    // Issue tile t+1's staging NOW (8 loads/thread), then wait only for the
    // OLDER 8 (tile t's data, issued a full tile ago). T4 counted vmcnt.
    if (t + 1 < nt) {
      const int k1 = (t + 1) << 6;
      stage_half(Ab + k1, lda, An, tid);
      stage_half(Ab + (size_t)128 * lda + k1, lda, An + 8192, tid);
      stage_half(Bb + k1, ldb, Bn, tid);
      stage_half(Bb + (size_t)128 * ldb + k1, ldb, Bn + 8192, tid);
      asm volatile("s_waitcnt vmcnt(8)" ::: "memory");
    } else {
      asm volatile("s_waitcnt vmcnt(0)" ::: "memory");
    }
    __builtin_amdgcn_s_barrier();
#pragma unroll
    for (int q = 0; q < 4; ++q) {
      short8 afr[4][2], bfr[2][2];
#pragma unroll
      for (int i = 0; i < 4; ++i) {
        int r = wm + (q >> 1) * 64 + i * 16 + lr;
#pragma unroll
        for (int kx = 0; kx < 2; ++kx)
          afr[i][kx] = *(const short8*)&Ac[r * 64 + ((kx * 4 + lg) ^ (r & 7)) * 8];
      }
#pragma unroll
      for (int j = 0; j < 2; ++j) {
        int r = wn + (q & 1) * 32 + j * 16 + lr;
#pragma unroll
        for (int kx = 0; kx < 2; ++kx)
          bfr[j][kx] = *(const short8*)&Bc[r * 64 + ((kx * 4 + lg) ^ (r & 7)) * 8];
      }
      __builtin_amdgcn_s_barrier();
      asm volatile("s_waitcnt lgkmcnt(0)" ::: "memory");
      __builtin_amdgcn_sched_barrier(0);
      __builtin_amdgcn_s_setprio(1);
#pragma unroll
      for (int kx = 0; kx < 2; ++kx)
#pragma unroll
        for (int i = 0; i < 4; ++i)
#pragma unroll
          for (int j = 0; j < 2; ++j)
            acc[(q >> 1) * 4 + i][(q & 1) * 2 + j] =
                __builtin_amdgcn_mfma_f32_16x16x32_bf16(
                    afr[i][kx], bfr[j][kx],
                    acc[(q >> 1) * 4 + i][(q & 1) * 2 + j], 0, 0, 0);
      __builtin_amdgcn_s_setprio(0);
      __builtin_amdgcn_sched_barrier(0);
      __builtin_amdgcn_s_barrier();
    }
  }

#pragma unroll
  for (int i = 0; i < 8; ++i) {
    int rbase = m0 + wm + i * 16 + lg * 4;
#pragma unroll
    for (int j = 0; j < 4; ++j) {
      int col = n0 + wn + j * 16 + lr;
      if (col < N) {
#pragma unroll
        for (int e = 0; e < 4; ++e)
          C[(size_t)(rbase + e) * ldc + col] = f2b(acc[i][j][e]);
      }
    }
  }
}

// ---------------- Generic bf16 NT GEMM (global_load_lds staging) -----------
#define BM 128
#define BN 128
#define BK 64

template<int EPI>
__global__ __launch_bounds__(256) void gemm_kernel(
    const u16b* __restrict__ A, const u16b* __restrict__ B, void* __restrict__ Cptr,
    const int* __restrict__ flag, int M, int N, int K, int lda, int ldb, int ldc) {
  __shared__ u16b As[BM * BK];
  __shared__ u16b Bs[BN * BK];
  const int tid = threadIdx.x;
  const int nbx = gridDim.x;
  const int id = xcd_swz(blockIdx.y * nbx + blockIdx.x, nbx * gridDim.y);
  const int n0 = (id % nbx) * BN;
  const int m0 = (id / nbx) * BM;
  const int wave = tid >> 6, lane = tid & 63;
  const int wm = (wave >> 1) * 64, wn = (wave & 1) * 64;
  const int lr = lane & 15, lg = lane >> 4;
  u16b* C = (u16b*)Cptr;
  float* Cf = (float*)Cptr;
  const int fl = (EPI == 3) ? flag[0] : 1;

  f32x4 acc[4][4] = {};

  for (int k0 = 0; k0 < K; k0 += BK) {
    stage_tile(A + (size_t)m0 * lda + k0, lda, As, wave, lane);
    stage_tile(B + (size_t)n0 * ldb + k0, ldb, Bs, wave, lane);
    __syncthreads();
#pragma unroll
    for (int kk = 0; kk < BK; kk += 32) {
      short8 afr[4], bfr[4];
#pragma unroll
      for (int i = 0; i < 4; ++i) {
        int r = wm + i * 16 + lr;
        afr[i] = *(const short8*)&As[r * 64 + (((kk >> 3) + lg) ^ (r & 7)) * 8];
      }
#pragma unroll
      for (int j = 0; j < 4; ++j) {
        int r = wn + j * 16 + lr;
        bfr[j] = *(const short8*)&Bs[r * 64 + (((kk >> 3) + lg) ^ (r & 7)) * 8];
      }
#pragma unroll
      for (int i = 0; i < 4; ++i)
#pragma unroll
        for (int j = 0; j < 4; ++j)
          acc[i][j] = __builtin_amdgcn_mfma_f32_16x16x32_bf16(
              afr[i], bfr[j], acc[i][j], 0, 0, 0);
    }
    __syncthreads();
  }

#pragma unroll
  for (int i = 0; i < 4; ++i) {
    int rbase = m0 + wm + i * 16 + lg * 4;
#pragma unroll
    for (int j = 0; j < 4; ++j) {
      int col = n0 + wn + j * 16 + lr;
      if (col < N) {
#pragma unroll
        for (int e = 0; e < 4; ++e) {
          float v = acc[i][j][e];
          size_t ci = (size_t)(rbase + e) * ldc + col;
          if (EPI == 3) {
            if (fl) C[ci] = f2b(v); else Cf[ci] = v;
          } else {
            C[ci] = f2b(v);
          }
        }
      }
    }
  }
}

// ---------------- Dual-half NT GEMM (stacked M; global_load_lds staging) ---
template<int EPI>
__global__ __launch_bounds__(256) void gemm2_kernel(
    const u16b* __restrict__ A, const u16b* __restrict__ B1,
    const u16b* __restrict__ B2, u16b* __restrict__ C1, u16b* __restrict__ C2,
    const u16b* __restrict__ bias1, const u16b* __restrict__ bias2,
    float* __restrict__ aux1, float* __restrict__ aux2,
    int Mhalf, int N, int K, int lda, int ldb, int ldc1, int ldc2) {
  __shared__ u16b As[BM * BK];
  __shared__ u16b Bs[BN * BK];
  const int tid = threadIdx.x;
  const int nbx = gridDim.x;
  const int id = xcd_swz(blockIdx.y * nbx + blockIdx.x, nbx * gridDim.y);
  const int n0 = (id % nbx) * BN;
  const int m0 = (id / nbx) * BM;
  const int hi = (m0 >= Mhalf);
  const u16b* B = hi ? B2 : B1;
  u16b* C = hi ? C2 : C1;
  const u16b* bias = hi ? bias2 : bias1;
  float* aux = hi ? aux2 : aux1;
  const int ldc = hi ? ldc2 : ldc1;
  const int mloc = m0 - (hi ? Mhalf : 0);
  const int wave = tid >> 6, lane = tid & 63;
  const int wm = (wave >> 1) * 64, wn = (wave & 1) * 64;
  const int lr = lane & 15, lg = lane >> 4;

  f32x4 acc[4][4] = {};

  for (int k0 = 0; k0 < K; k0 += BK) {
    stage_tile(A + (size_t)m0 * lda + k0, lda, As, wave, lane);
    stage_tile(B + (size_t)n0 * ldb + k0, ldb, Bs, wave, lane);
    __syncthreads();
#pragma unroll
    for (int kk = 0; kk < BK; kk += 32) {
      short8 afr[4], bfr[4];
#pragma unroll
      for (int i = 0; i < 4; ++i) {
        int r = wm + i * 16 + lr;
        afr[i] = *(const short8*)&As[r * 64 + (((kk >> 3) + lg) ^ (r & 7)) * 8];
      }
#pragma unroll
      for (int j = 0; j < 4; ++j) {
        int r = wn + j * 16 + lr;
        bfr[j] = *(const short8*)&Bs[r * 64 + (((kk >> 3) + lg) ^ (r & 7)) * 8];
      }
#pragma unroll
      for (int i = 0; i < 4; ++i)
#pragma unroll
        for (int j = 0; j < 4; ++j)
          acc[i][j] = __builtin_amdgcn_mfma_f32_16x16x32_bf16(
              afr[i], bfr[j], acc[i][j], 0, 0, 0);
    }
    __syncthreads();
  }

#pragma unroll
  for (int i = 0; i < 4; ++i) {
    int rbase = mloc + wm + i * 16 + lg * 4;
#pragma unroll
    for (int j = 0; j < 4; ++j) {
      int col = n0 + wn + j * 16 + lr;
      if (col < N) {
        float bv = (EPI == 1) ? b2f(bias[col]) : 0.f;
#pragma unroll
        for (int e = 0; e < 4; ++e) {
          float v = acc[i][j][e];
          if (EPI == 1) v = softplus_fast(v + bv);
          C[(size_t)(rbase + e) * ldc + col] = f2b(v);
          if (EPI == 2 && col >= 64)
            aux[(size_t)(rbase + e) * 32 + (col - 64)] = v;
        }
      }
    }
  }
}

// ---------------- x_dbl GEMM, split-K=2, f32 partials ----------------------
__global__ __launch_bounds__(256) void gemm2s_kernel(
    const u16b* __restrict__ A, const u16b* __restrict__ B1,
    const u16b* __restrict__ B2, float* __restrict__ P,
    int Mhalf, int Ksplit, int lda, int ldb) {
  __shared__ u16b As[BM * BK];
  __shared__ u16b Bs[BN * BK];
  const int tid = threadIdx.x;
  const int ks = blockIdx.x;
  const int m0 = blockIdx.y * BM;
  const int hi = (m0 >= Mhalf);
  const u16b* B = hi ? B2 : B1;
  const int wave = tid >> 6, lane = tid & 63;
  const int wm = (wave >> 1) * 64, wn = (wave & 1) * 64;
  const int lr = lane & 15, lg = lane >> 4;

  f32x4 acc[4][4] = {};

  const int kbeg = ks * Ksplit;
  for (int k0 = kbeg; k0 < kbeg + Ksplit; k0 += BK) {
    stage_tile(A + (size_t)m0 * lda + k0, lda, As, wave, lane);
    stage_tile(B + k0, ldb, Bs, wave, lane);
    __syncthreads();
#pragma unroll
    for (int kk = 0; kk < BK; kk += 32) {
      short8 afr[4], bfr[4];
#pragma unroll
      for (int i = 0; i < 4; ++i) {
        int r = wm + i * 16 + lr;
        afr[i] = *(const short8*)&As[r * 64 + (((kk >> 3) + lg) ^ (r & 7)) * 8];
      }
#pragma unroll
      for (int j = 0; j < 4; ++j) {
        int r = wn + j * 16 + lr;
        bfr[j] = *(const short8*)&Bs[r * 64 + (((kk >> 3) + lg) ^ (r & 7)) * 8];
      }
#pragma unroll
      for (int i = 0; i < 4; ++i)
#pragma unroll
        for (int j = 0; j < 4; ++j)
          acc[i][j] = __builtin_amdgcn_mfma_f32_16x16x32_bf16(
              afr[i], bfr[j], acc[i][j], 0, 0, 0);
    }
    __syncthreads();
  }

  float* Pk = P + (size_t)ks * ((size_t)2 * Mhalf) * 128;
#pragma unroll
  for (int i = 0; i < 4; ++i) {
    int rg = m0 + wm + i * 16 + lg * 4;
#pragma unroll
    for (int j = 0; j < 4; ++j) {
      int col = wn + j * 16 + lr;
#pragma unroll
      for (int e = 0; e < 4; ++e)
        Pk[(size_t)(rg + e) * 128 + col] = acc[i][j][e];
    }
  }
}

__global__ __launch_bounds__(256) void xdbl_reduce_kernel(
    const float* __restrict__ P, u16b* __restrict__ xdf,
    u16b* __restrict__ xdb, float* __restrict__ bcf,
    float* __restrict__ bcb) {
  int e = blockIdx.x * 256 + threadIdx.x;   // over 16384*128
  int col = e & 127;
  int m = e >> 7;
  if (col >= 96) return;
  float v = P[(size_t)e] + P[(size_t)e + (size_t)16384 * 128];
  int hi = (m >= MROWS);
  int mloc = m - (hi ? MROWS : 0);
  u16b* C = hi ? xdb : xdf;
  C[(size_t)mloc * 96 + col] = f2b(v);
  if (col >= 64) {
    float* aux = hi ? bcb : bcf;
    aux[(size_t)mloc * 32 + (col - 64)] = v;
  }
}

// ---------------- Dual depthwise causal conv + SiLU ------------------------
__global__ __launch_bounds__(256) void conv_kernel(
    const u16b* __restrict__ xz, const u16b* __restrict__ cwf,
    const u16b* __restrict__ cbf, const u16b* __restrict__ cwb,
    const u16b* __restrict__ cbb, u16b* __restrict__ u_f,
    u16b* __restrict__ u_b) {
  int gid = blockIdx.x * 256 + threadIdx.x;
  int d = gid & (DI - 1);
  int m = gid >> 11;
  int b = m >> 11;
  int l = m & (LSEQ - 1);
  const u16b* xcol = xz + ((size_t)b * LSEQ) * (2 * DI) + d;
  float xv[7];
#pragma unroll
  for (int t = 0; t < 7; ++t) {
    int ll = l + t - 3;
    xv[t] = (ll >= 0 && ll < LSEQ) ? b2f(xcol[(size_t)ll * (2 * DI)]) : 0.f;
  }
  float af = b2f(cbf[d]);
#pragma unroll
  for (int k = 0; k < 4; ++k) af = fmaf(b2f(cwf[d * 4 + k]), xv[k], af);
  float ab = b2f(cbb[d]);
#pragma unroll
  for (int j = 0; j < 4; ++j) ab = fmaf(b2f(cwb[d * 4 + 3 - j]), xv[3 + j], ab);
  float sf = af * fast_rcp(1.f + __expf(-af));
  float sb = ab * fast_rcp(1.f + __expf(-ab));
  u_f[(size_t)m * DI + d] = f2b(sf);
  u_b[((size_t)b * LSEQ + (LSEQ - 1 - l)) * DI + d] = f2b(sb);
}

// ---------------- Chunked selective scan ----------------------------------
__device__ __forceinline__ bool detect_intA(const u16b* alog, int d, float* An2) {
  bool fast = true;
#pragma unroll
  for (int n = 0; n < DS; ++n) {
    float a = __expf(b2f(alog[d * DS + n]));
    An2[n] = -a * 1.44269504088896f;
    fast = fast && (fabsf(a - (float)(n + 1)) < 0.02f * (float)(n + 1));
  }
  return fast;
}

#define CHUNK_BODY_FAST() do {                                        \
    float du = cd * cu; s += cd;                                      \
    float dA[DS]; pow_ladder(__expf(-cd), dA);                        \
    _Pragma("unroll") for (int n = 0; n < DS; ++n)                    \
      h[n] = fmaf(dA[n], h[n], du * bl[n]);                           \
    bl += 32;                                                         \
  } while (0)

#define CHUNK_BODY_SLOW() do {                                        \
    float du = cd * cu; s += cd;                                      \
    _Pragma("unroll") for (int n = 0; n < DS; ++n) {                  \
      float dA = exp2f(cd * An2[n]);                                  \
      h[n] = fmaf(dA, h[n], du * bl[n]);                              \
    }                                                                 \
    bl += 32;                                                         \
  } while (0)

__global__ __launch_bounds__(256) void scan_chunk_kernel(
    const u16b* __restrict__ xz, const u16b* __restrict__ u_f,
    const u16b* __restrict__ u_b, const u16b* __restrict__ dltb,
    const float* __restrict__ bc_f, const float* __restrict__ bc_b,
    const u16b* __restrict__ alog_f, const u16b* __restrict__ alog_b,
    float* __restrict__ hstate, float* __restrict__ sdelta) {
  int bx = blockIdx.x;
  int dblk = bx & 7;
  int chunk = (bx >> 3) & 31;
  int b = (bx >> 8) & 3;
  int dir = bx >> 10;
  int d = dblk * 256 + threadIdx.x;

  const u16b* uptr = dir ? u_b : u_f;
  const u16b* dlt = dir ? dltb : xz;
  const int ldd = dir ? DI : 2 * DI;
  const float* bcp = dir ? bc_b : bc_f;
  const u16b* alog = dir ? alog_b : alog_f;

  const size_t mb = (size_t)b * LSEQ + (size_t)chunk * CLEN;
  const float* bl = bcp + mb * 32;
  float An2[DS];
  bool fastA = detect_intA(alog, d, An2);

  float h[DS];
#pragma unroll
  for (int n = 0; n < DS; ++n) h[n] = 0.f;
  float s = 0.f;
  unsigned od = (unsigned)mb * (unsigned)ldd + (unsigned)d;
  unsigned ou = (unsigned)mb * DI + (unsigned)d;
  float nd = b2f(dlt[od]);
  float nu = b2f(uptr[ou]);
  float cd, cu;
  if (fastA) {
#pragma unroll 4
    for (int l = 0; l < CLEN - 1; ++l) {
      cd = nd; cu = nu;
      od += ldd; ou += DI;
      nd = b2f(dlt[od]); nu = b2f(uptr[ou]);
      CHUNK_BODY_FAST();
    }
    cd = nd; cu = nu;
    CHUNK_BODY_FAST();
  } else {
#pragma unroll 4
    for (int l = 0; l < CLEN - 1; ++l) {
      cd = nd; cu = nu;
      od += ldd; ou += DI;
      nd = b2f(dlt[od]); nu = b2f(uptr[ou]);
      CHUNK_BODY_SLOW();
    }
    cd = nd; cu = nu;
    CHUNK_BODY_SLOW();
  }
  size_t slot = (size_t)((dir * 4 + b) * 32 + chunk) * 2048 + d;
  float* hp = hstate + slot * 16;
#pragma unroll
  for (int i = 0; i < 4; ++i)
    ((f32x4*)hp)[i] = *(f32x4*)&h[i * 4];
  sdelta[slot] = s;
}

// Carry: one thread per (dir,b,d,n) = 262144 threads (1024 blocks).
__global__ __launch_bounds__(256) void scan_carry_kernel(
    const u16b* __restrict__ alog_f, const u16b* __restrict__ alog_b,
    float* __restrict__ hstate, const float* __restrict__ sdelta) {
  int gid = blockIdx.x * 256 + threadIdx.x;
  int n = gid & (DS - 1);
  int d = (gid >> 4) & (DI - 1);
  int b = (gid >> 15) & 3;
  int dir = gid >> 17;
  const u16b* alog = dir ? alog_b : alog_f;
  float An2 = -__expf(b2f(alog[d * DS + n])) * 1.44269504088896f;
  float h = 0.f;
  size_t base = (size_t)((dir * 4 + b) * 32) * 2048 + d;
  for (int c = 0; c < NCH; ++c) {
    size_t slot = base + (size_t)c * 2048;
    float sdv = sdelta[slot];
    float* hp = hstate + slot * 16 + n;
    float hl = *hp;
    float P = exp2f(An2 * sdv);
    float nh = fmaf(P, h, hl);
    *hp = h;   // carry-in state for chunk c (state before chunk c)
    h = nh;
  }
}

#define APPLY_BODY_FAST() do {                                        \
    float du = cd * cu;                                               \
    float dA[DS]; pow_ladder(__expf(-cd), dA);                        \
    float y0 = 0.f, y1 = 0.f;                                         \
    _Pragma("unroll") for (int n = 0; n < DS; n += 2) {               \
      h[n] = fmaf(dA[n], h[n], du * bl[n]);                           \
      y0 = fmaf(h[n], bl[16 + n], y0);                                \
      h[n + 1] = fmaf(dA[n + 1], h[n + 1], du * bl[n + 1]);           \
      y1 = fmaf(h[n + 1], bl[17 + n], y1);                            \
    }                                                                 \
    float sz = cz * fast_rcp(1.f + __expf(-cz));                      \
    float out = (y0 + y1 + Dd * cu) * sz;                             \
    uptr[oo] = f2b_cvt(out); oo += DI; bl += 32;                      \
  } while (0)

#define APPLY_BODY_SLOW() do {                                        \
    float du = cd * cu;                                               \
    float y = 0.f;                                                    \
    _Pragma("unroll") for (int n = 0; n < DS; ++n) {                  \
      float dA = exp2f(cd * An2[n]);                                  \
      h[n] = fmaf(dA, h[n], du * bl[n]);                              \
      y = fmaf(h[n], bl[16 + n], y);                                  \
    }                                                                 \
    float sz = cz * fast_rcp(1.f + __expf(-cz));                      \
    float out = (y + Dd * cu) * sz;                                   \
    uptr[oo] = f2b_cvt(out); oo += DI; bl += 32;                      \
  } while (0)

__global__ __launch_bounds__(256) void scan_apply_kernel(
    const u16b* __restrict__ xz, u16b* __restrict__ u_f,
    u16b* __restrict__ u_b, const u16b* __restrict__ dltb,
    const float* __restrict__ bc_f, const float* __restrict__ bc_b,
    const u16b* __restrict__ alog_f, const u16b* __restrict__ alog_b,
    const u16b* __restrict__ dv_f, const u16b* __restrict__ dv_b,
    const float* __restrict__ hstate) {
  int bx = blockIdx.x;
  int dblk = bx & 7;
  int chunk = (bx >> 3) & 31;
  int b = (bx >> 8) & 3;
  int dir = bx >> 10;
  int d = dblk * 256 + threadIdx.x;

  u16b* uptr = dir ? u_b : u_f;
  const u16b* dlt = dir ? dltb : xz;
  const int ldd = dir ? DI : 2 * DI;
  const float* bcp = dir ? bc_b : bc_f;
  const u16b* alog = dir ? alog_b : alog_f;
  const u16b* dv = dir ? dv_b : dv_f;

  const size_t mb0 = (size_t)b * LSEQ;
  const size_t mb = mb0 + (size_t)chunk * CLEN;
  const float* bl = bcp + mb * 32;
  float An2[DS];
  bool fastA = detect_intA(alog, d, An2);
  float Dd = b2f(dv[d]);
  float h[DS];
  {
    size_t slot = (size_t)((dir * 4 + b) * 32 + chunk) * 2048 + d;
    const float* hp = hstate + slot * 16;
#pragma unroll
    for (int i = 0; i < 4; ++i)
      *(f32x4*)&h[i * 4] = ((const f32x4*)hp)[i];
  }

  size_t zs0 = dir ? (mb0 + (LSEQ - 1 - (size_t)chunk * CLEN)) : mb;
  const int zst = dir ? -(2 * DI) : (2 * DI);
  unsigned od = (unsigned)mb * (unsigned)ldd + (unsigned)d;
  unsigned ou = (unsigned)mb * DI + (unsigned)d;
  unsigned oo = ou;
  int oz = (int)zs0 * (2 * DI) + DI + d;
  float nd = b2f(dlt[od]);
  float nu = b2f(uptr[ou]);
  float nz = b2f(xz[oz]);
  float cd, cu, cz;
  if (fastA) {
#pragma unroll 4
    for (int l = 0; l < CLEN - 1; ++l) {
      cd = nd; cu = nu; cz = nz;
      od += ldd; ou += DI; oz += zst;
      nd = b2f(dlt[od]); nu = b2f(uptr[ou]); nz = b2f(xz[oz]);
      APPLY_BODY_FAST();
    }
    cd = nd; cu = nu; cz = nz;
    APPLY_BODY_FAST();
  } else {
#pragma unroll 4
    for (int l = 0; l < CLEN - 1; ++l) {
      cd = nd; cu = nu; cz = nz;
      od += ldd; ou += DI; oz += zst;
      nd = b2f(dlt[od]); nu = b2f(uptr[ou]); nz = b2f(xz[oz]);
      APPLY_BODY_SLOW();
    }
    cd = nd; cu = nu; cz = nz;
    APPLY_BODY_SLOW();
  }
}

// ---------------- Combine: yc[m] = (y_f[m] + y_b[rev(m)]) / 2 --------------
__global__ __launch_bounds__(256) void combine_kernel(
    const u16b* __restrict__ yf, const u16b* __restrict__ yb_rev,
    u16b* __restrict__ yc) {
  size_t i = ((size_t)blockIdx.x * 256 + threadIdx.x) * 8;
  size_t m = i >> 11;
  size_t dcol = i & (DI - 1);
  size_t mr = m ^ (LSEQ - 1);
  uint4 a = *(const uint4*)(yf + m * DI + dcol);
  uint4 b = *(const uint4*)(yb_rev + mr * DI + dcol);
  const u16b* ap = (const u16b*)&a;
  const u16b* bp = (const u16b*)&b;
  uint4 o;
  u16b* op = (u16b*)&o;
#pragma unroll
  for (int j = 0; j < 8; ++j) op[j] = f2b(0.5f * (b2f(ap[j]) + b2f(bp[j])));
  *(uint4*)(yc + i) = o;
}

extern "C" void kernel_launch(void* const* d_in, const int* in_sizes, int n_in,
                              void* d_out, int out_size, void* d_ws,
                              size_t ws_size, hipStream_t stream) {
  char* ws = (char*)d_ws;
  u16b* xz    = (u16b*)(ws);
  u16b* u_f   = (u16b*)(ws + 67108864);
  u16b* u_b   = (u16b*)(ws + 100663296);
  u16b* arena = (u16b*)(ws + 134217728);
  u16b* xdf   = (u16b*)(ws + 167772160);
  u16b* xdb   = (u16b*)(ws + 169345024);
  float* bcf  = (float*)(ws + 170917888);
  float* bcb  = (float*)(ws + 171966464);
  u16b* opw_c  = (u16b*)(ws + 173015040);   // 4 MiB
  u16b* xpwf_c = (u16b*)(ws + 177209344);
  u16b* xpwb_c = (u16b*)(ws + 177602560);
  u16b* dpwf_c = (u16b*)(ws + 177995776);
  u16b* dpwb_c = (u16b*)(ws + 178257920);
  u16b* cwf_c  = (u16b*)(ws + 178520064);
  u16b* cwb_c  = (u16b*)(ws + 178536448);
  u16b* cbf_c  = (u16b*)(ws + 178552832);
  u16b* cbb_c  = (u16b*)(ws + 178556928);
  u16b* dpbf_c = (u16b*)(ws + 178561024);
  u16b* dpbb_c = (u16b*)(ws + 178565120);
  u16b* alf_c  = (u16b*)(ws + 178569216);
  u16b* alb_c  = (u16b*)(ws + 178634752);
  u16b* dvf_c  = (u16b*)(ws + 178700288);
  u16b* dvb_c  = (u16b*)(ws + 178704384);
  int*  flag   = (int*)(ws + 178708480);
  float* hstate = (float*)(ws + 178712576); // 32 MiB
  float* sdelta = (float*)(ws + 212267008); // 2 MiB -> end 214,364,160

  u16b* hs_c  = arena;           // 16 MiB, dead after in-proj GEMM
  u16b* inw_c = arena + 8388608; // 8 MiB, dead after in-proj GEMM
  float* Pbuf = (float*)arena;   // 16.8 MiB, live gemm2s..reduce only
  u16b* dltb  = arena;           // live dt-GEMM..scan
  u16b* y_c   = arena;           // live combine..out-proj

  dim3 blk(256);
  // 0) sniff dtype; canonicalize all inputs to bf16 ONCE (O(bytes))
  sniff_kernel<<<dim3(1), dim3(64), 0, stream>>>((const unsigned int*)d_in[0], flag);
  convert_kernel<<<dim3(4096), blk, 0, stream>>>(d_in[0], hs_c, 8388608, flag);
  convert_kernel<<<dim3(2048), blk, 0, stream>>>(d_in[1], inw_c, 4194304, flag);
  convert_kernel<<<dim3(1024), blk, 0, stream>>>(d_in[16], opw_c, 2097152, flag);
  SmallTab st = {{d_in[2], d_in[3], d_in[4], d_in[5], d_in[6], d_in[7], d_in[8],
                  d_in[9], d_in[10], d_in[11], d_in[12], d_in[13], d_in[14],
                  d_in[15]},
                 {cwf_c, cbf_c, cwb_c, cbb_c, xpwf_c, dpwf_c, dpbf_c, xpwb_c,
                  dpwb_c, dpbb_c, alf_c, alb_c, dvf_c, dvb_c}};
  convert_small_kernel<<<dim3(366), blk, 0, stream>>>(st, flag);

  // 1) xz = hs @ in_proj_w^T  (256^2 counted-vmcnt 8-phase)
  gemm8_kernel<<<dim3(16, 32), dim3(512), 0, stream>>>(hs_c, inw_c, xz,
      MROWS, 2 * DI, DM, DM, DM, 2 * DI);
  // 2) conv both dirs
  conv_kernel<<<dim3(65536), blk, 0, stream>>>(xz, cwf_c, cbf_c, cwb_c, cbb_c,
                                               u_f, u_b);
  // 3) x_dbl both dirs: split-K=2 into f32 partials (arena), then reduce
  gemm2s_kernel<<<dim3(2, 128), blk, 0, stream>>>(u_f, xpwf_c, xpwb_c, Pbuf,
      MROWS, 1024, DI, DI);
  xdbl_reduce_kernel<<<dim3(8192), blk, 0, stream>>>(Pbuf, xdf, xdb, bcf, bcb);
  // 4) delta both dirs, one launch; fwd C -> xz x-half (ldc=4096)
  gemm2_kernel<1><<<dim3(16, 128), blk, 0, stream>>>(xdf, dpwf_c, dpwb_c,
      xz, dltb, dpbf_c, dpbb_c, nullptr, nullptr, MROWS, DI, 64, 96, 64,
      2 * DI, DI);
  // 5) chunked scan: pass1 -> carry -> pass2
  scan_chunk_kernel<<<dim3(2048), blk, 0, stream>>>(xz, u_f, u_b, dltb, bcf,
      bcb, alf_c, alb_c, hstate, sdelta);
  scan_carry_kernel<<<dim3(1024), blk, 0, stream>>>(alf_c, alb_c, hstate, sdelta);
  scan_apply_kernel<<<dim3(2048), blk, 0, stream>>>(xz, u_f, u_b, dltb, bcf,
      bcb, alf_c, alb_c, dvf_c, dvb_c, hstate);
  // 6) combine -> y_c
  combine_kernel<<<dim3(8192), blk, 0, stream>>>(u_f, u_b, y_c);
  // 7) out = y @ out_proj_w^T -> d_out (dtype per flag)
  gemm_kernel<3><<<dim3(8, 64), blk, 0, stream>>>(y_c, opw_c, d_out, flag,
      MROWS, DM, DI, DI, DI, DM);
}

// Round 6
// 539.270 us; speedup vs baseline: 1.0418x; 1.0418x over previous
//
#include <hip/hip_runtime.h>

// BiMamba. R6: consolidation.
//  - gemm8 reverted to R4 schedule (per-phase fine-interleaved staging,
//    boundary vmcnt(0)). R5's coarse top-of-loop staging was m196's
//    documented -19% failure mode.
//  - all 17 input conversions merged into ONE launch (prefix table).
//  - scan_chunk skips chunk 31 (its h/sdelta are dead: carry's last
//    update is discarded); carry guarded to never read that slot.

#define Bsz  4
#define LSEQ 2048
#define DM   1024
#define DI   2048
#define DS   16
#define MROWS (Bsz * LSEQ) // 8192
#define NCH  32
#define CLEN 64

typedef unsigned short u16b;
typedef __attribute__((ext_vector_type(8))) short short8;
typedef __attribute__((ext_vector_type(4))) float f32x4;
typedef __attribute__((address_space(3))) unsigned int lds_u32;
typedef const __attribute__((address_space(1))) unsigned int glb_u32;

__device__ __forceinline__ float b2f(u16b u) {
  union { unsigned int i; float f; } x; x.i = ((unsigned int)u) << 16; return x.f;
}
__device__ __forceinline__ u16b f2b(float f) {
  union { float f; unsigned int i; } x; x.f = f;
  unsigned int r = x.i + 0x7FFFu + ((x.i >> 16) & 1u);
  return (u16b)(r >> 16);
}
__device__ __forceinline__ u16b f2b_cvt(float f) {
  unsigned int r;
  asm("v_cvt_pk_bf16_f32 %0, %1, %1" : "=v"(r) : "v"(f));
  return (u16b)r;
}
__device__ __forceinline__ float fast_rcp(float x) {
  return __builtin_amdgcn_rcpf(x);
}
__device__ __forceinline__ float softplus_fast(float v) {
  float e = __expf(-fabsf(v));
  return fmaxf(v, 0.f) + __logf(1.f + e);
}
__device__ __forceinline__ void pow_ladder(float q, float* dA) {
  float q2 = q * q, q3 = q2 * q, q4 = q2 * q2;
  float q5 = q4 * q, q6 = q4 * q2, q7 = q4 * q3, q8 = q4 * q4;
  dA[0] = q;  dA[1] = q2;  dA[2] = q3;  dA[3] = q4;
  dA[4] = q5; dA[5] = q6;  dA[6] = q7;  dA[7] = q8;
  dA[8] = q8 * q;  dA[9] = q8 * q2;  dA[10] = q8 * q3;  dA[11] = q8 * q4;
  dA[12] = q8 * q5; dA[13] = q8 * q6; dA[14] = q8 * q7; dA[15] = q8 * q8;
}

// Bijective XCD-aware block swizzle (requires nwg % 8 == 0; all our grids are).
__device__ __forceinline__ int xcd_swz(int id, int nwg) {
  int c = nwg >> 3;
  return (id & 7) * c + (id >> 3);
}

// ---- m97-style tile stage: 128 rows x 64 cols bf16, XOR-swizzled ----------
__device__ __forceinline__ void stage_tile(const u16b* gbase, int ld,
                                           u16b* lds, int wave, int lane) {
#pragma unroll
  for (int t = 0; t < 4; ++t) {
    int rb = wave * 32 + t * 8;
    int r = rb + (lane >> 3);
    int cb = (lane & 7) ^ (r & 7);
    const u16b* g = gbase + (size_t)r * ld + cb * 8;
    __builtin_amdgcn_global_load_lds((glb_u32*)g, (lds_u32*)(lds + rb * 64),
                                     16, 0, 0);
  }
}

// ---- 8-phase stage: one half-tile (128 rows x 64 cols), 512 threads -------
__device__ __forceinline__ void stage_half(const u16b* gbase, int ld,
                                           u16b* ldsbase, int tid) {
#pragma unroll
  for (int i2 = 0; i2 < 2; ++i2) {
    int rg = (tid >> 6) * 2 + i2;        // row-group of 8 rows, wave-uniform
    int row = rg * 8 + ((tid >> 3) & 7); // 0..127
    int cb = (tid & 7) ^ (row & 7);
    const u16b* g = gbase + (size_t)row * ld + cb * 8;
    __builtin_amdgcn_global_load_lds((glb_u32*)g,
                                     (lds_u32*)(ldsbase + rg * 8 * 64), 16, 0, 0);
  }
}

// ---------------- dtype sniffer -------------------------------------------
__global__ void sniff_kernel(const unsigned int* __restrict__ p,
                             int* __restrict__ flag) {
  unsigned int w = p[threadIdx.x];
  int e = (w >> 7) & 0xFF;
  unsigned long long m = __ballot(e >= 110 && e <= 135);
  if (threadIdx.x == 0) *flag = (__popcll(m) >= 32) ? 1 : 0;
}

// ---------------- merged converter: ALL inputs in one launch ---------------
struct ConvTab { const void* s[17]; u16b* d[17]; };
__global__ __launch_bounds__(256) void convert_all_kernel(
    ConvTab t, const int* __restrict__ flag) {
  // blocks per segment: hs 4096, inw 2048, opw 1024, then the 14 small.
  const int pref[18] = {0, 4096, 6144, 7168, 7172, 7173, 7177, 7178, 7274,
                        7338, 7339, 7435, 7499, 7500, 7516, 7532, 7533, 7534};
  int bx = blockIdx.x;
  int seg = 0;
#pragma unroll
  for (int i = 0; i < 17; ++i)
    if (bx >= pref[i + 1]) seg = i + 1;
  int idx = (bx - pref[seg]) * 2048 + threadIdx.x * 8;
  u16b* dst = t.d[seg];
  if (*flag) {
    *(uint4*)(dst + idx) = *(const uint4*)((const u16b*)t.s[seg] + idx);
  } else {
    const float* s = (const float*)t.s[seg];
    float4 a = *(const float4*)(s + idx);
    float4 b = *(const float4*)(s + idx + 4);
    u16b o[8] = {f2b(a.x), f2b(a.y), f2b(a.z), f2b(a.w),
                 f2b(b.x), f2b(b.y), f2b(b.z), f2b(b.w)};
    *(uint4*)(dst + idx) = *(uint4*)o;
  }
}

// ---------------- 256^2 8-phase bf16 NT GEMM (in-proj, R4 schedule) --------
__global__ __launch_bounds__(512, 2) void gemm8_kernel(
    const u16b* __restrict__ A, const u16b* __restrict__ B,
    u16b* __restrict__ C, int M, int N, int K, int lda, int ldb, int ldc) {
  __shared__ u16b As[2][256 * 64];
  __shared__ u16b Bs[2][256 * 64];
  const int tid = threadIdx.x;
  const int nbx = gridDim.x;
  const int id = xcd_swz(blockIdx.y * nbx + blockIdx.x, nbx * gridDim.y);
  const int n0 = (id % nbx) * 256;
  const int m0 = (id / nbx) * 256;
  const int wave = tid >> 6, lane = tid & 63;
  const int wm = (wave >> 2) * 128, wn = (wave & 3) * 64;
  const int lr = lane & 15, lg = lane >> 4;

  const u16b* Ab = A + (size_t)m0 * lda;
  const u16b* Bb = B + (size_t)n0 * ldb;
  const int nt = K >> 6;

  f32x4 acc[8][4] = {};

  // prologue: tile 0 -> buf0
  stage_half(Ab, lda, As[0], tid);
  stage_half(Ab + (size_t)128 * lda, lda, As[0] + 8192, tid);
  stage_half(Bb, ldb, Bs[0], tid);
  stage_half(Bb + (size_t)128 * ldb, ldb, Bs[0] + 8192, tid);
  asm volatile("s_waitcnt vmcnt(0)" ::: "memory");
  __builtin_amdgcn_s_barrier();

  for (int t = 0; t < nt; ++t) {
    const int cur = t & 1;
    const u16b* Ac = As[cur];
    const u16b* Bc = Bs[cur];
    u16b* An = As[cur ^ 1];
    u16b* Bn = Bs[cur ^ 1];
    const int k1 = (t + 1) << 6;
    const bool more = (t + 1 < nt);
#pragma unroll
    for (int q = 0; q < 4; ++q) {
      short8 afr[4][2], bfr[2][2];
#pragma unroll
      for (int i = 0; i < 4; ++i) {
        int r = wm + (q >> 1) * 64 + i * 16 + lr;
#pragma unroll
        for (int kx = 0; kx < 2; ++kx)
          afr[i][kx] = *(const short8*)&Ac[r * 64 + ((kx * 4 + lg) ^ (r & 7)) * 8];
      }
#pragma unroll
      for (int j = 0; j < 2; ++j) {
        int r = wn + (q & 1) * 32 + j * 16 + lr;
#pragma unroll
        for (int kx = 0; kx < 2; ++kx)
          bfr[j][kx] = *(const short8*)&Bc[r * 64 + ((kx * 4 + lg) ^ (r & 7)) * 8];
      }
      if (more) {
        if (q == 0) stage_half(Ab + k1, lda, An, tid);
        else if (q == 1) stage_half(Ab + (size_t)128 * lda + k1, lda, An + 8192, tid);
        else if (q == 2) stage_half(Bb + k1, ldb, Bn, tid);
        else stage_half(Bb + (size_t)128 * ldb + k1, ldb, Bn + 8192, tid);
      }
      __builtin_amdgcn_s_barrier();
      asm volatile("s_waitcnt lgkmcnt(0)" ::: "memory");
      __builtin_amdgcn_sched_barrier(0);
      __builtin_amdgcn_s_setprio(1);
#pragma unroll
      for (int kx = 0; kx < 2; ++kx)
#pragma unroll
        for (int i = 0; i < 4; ++i)
#pragma unroll
          for (int j = 0; j < 2; ++j)
            acc[(q >> 1) * 4 + i][(q & 1) * 2 + j] =
                __builtin_amdgcn_mfma_f32_16x16x32_bf16(
                    afr[i][kx], bfr[j][kx],
                    acc[(q >> 1) * 4 + i][(q & 1) * 2 + j], 0, 0, 0);
      __builtin_amdgcn_s_setprio(0);
      __builtin_amdgcn_sched_barrier(0);
      __builtin_amdgcn_s_barrier();
    }
    // tile boundary: all of tile t+1's staging must land before next reads.
    asm volatile("s_waitcnt vmcnt(0)" ::: "memory");
    __builtin_amdgcn_s_barrier();
  }

#pragma unroll
  for (int i = 0; i < 8; ++i) {
    int rbase = m0 + wm + i * 16 + lg * 4;
#pragma unroll
    for (int j = 0; j < 4; ++j) {
      int col = n0 + wn + j * 16 + lr;
      if (col < N) {
#pragma unroll
        for (int e = 0; e < 4; ++e)
          C[(size_t)(rbase + e) * ldc + col] = f2b(acc[i][j][e]);
      }
    }
  }
}

// ---------------- Generic bf16 NT GEMM (global_load_lds staging) -----------
#define BM 128
#define BN 128
#define BK 64

template<int EPI>
__global__ __launch_bounds__(256) void gemm_kernel(
    const u16b* __restrict__ A, const u16b* __restrict__ B, void* __restrict__ Cptr,
    const int* __restrict__ flag, int M, int N, int K, int lda, int ldb, int ldc) {
  __shared__ u16b As[BM * BK];
  __shared__ u16b Bs[BN * BK];
  const int tid = threadIdx.x;
  const int nbx = gridDim.x;
  const int id = xcd_swz(blockIdx.y * nbx + blockIdx.x, nbx * gridDim.y);
  const int n0 = (id % nbx) * BN;
  const int m0 = (id / nbx) * BM;
  const int wave = tid >> 6, lane = tid & 63;
  const int wm = (wave >> 1) * 64, wn = (wave & 1) * 64;
  const int lr = lane & 15, lg = lane >> 4;
  u16b* C = (u16b*)Cptr;
  float* Cf = (float*)Cptr;
  const int fl = (EPI == 3) ? flag[0] : 1;

  f32x4 acc[4][4] = {};

  for (int k0 = 0; k0 < K; k0 += BK) {
    stage_tile(A + (size_t)m0 * lda + k0, lda, As, wave, lane);
    stage_tile(B + (size_t)n0 * ldb + k0, ldb, Bs, wave, lane);
    __syncthreads();
#pragma unroll
    for (int kk = 0; kk < BK; kk += 32) {
      short8 afr[4], bfr[4];
#pragma unroll
      for (int i = 0; i < 4; ++i) {
        int r = wm + i * 16 + lr;
        afr[i] = *(const short8*)&As[r * 64 + (((kk >> 3) + lg) ^ (r & 7)) * 8];
      }
#pragma unroll
      for (int j = 0; j < 4; ++j) {
        int r = wn + j * 16 + lr;
        bfr[j] = *(const short8*)&Bs[r * 64 + (((kk >> 3) + lg) ^ (r & 7)) * 8];
      }
#pragma unroll
      for (int i = 0; i < 4; ++i)
#pragma unroll
        for (int j = 0; j < 4; ++j)
          acc[i][j] = __builtin_amdgcn_mfma_f32_16x16x32_bf16(
              afr[i], bfr[j], acc[i][j], 0, 0, 0);
    }
    __syncthreads();
  }

#pragma unroll
  for (int i = 0; i < 4; ++i) {
    int rbase = m0 + wm + i * 16 + lg * 4;
#pragma unroll
    for (int j = 0; j < 4; ++j) {
      int col = n0 + wn + j * 16 + lr;
      if (col < N) {
#pragma unroll
        for (int e = 0; e < 4; ++e) {
          float v = acc[i][j][e];
          size_t ci = (size_t)(rbase + e) * ldc + col;
          if (EPI == 3) {
            if (fl) C[ci] = f2b(v); else Cf[ci] = v;
          } else {
            C[ci] = f2b(v);
          }
        }
      }
    }
  }
}

// ---------------- Dual-half NT GEMM (stacked M; global_load_lds staging) ---
template<int EPI>
__global__ __launch_bounds__(256) void gemm2_kernel(
    const u16b* __restrict__ A, const u16b* __restrict__ B1,
    const u16b* __restrict__ B2, u16b* __restrict__ C1, u16b* __restrict__ C2,
    const u16b* __restrict__ bias1, const u16b* __restrict__ bias2,
    float* __restrict__ aux1, float* __restrict__ aux2,
    int Mhalf, int N, int K, int lda, int ldb, int ldc1, int ldc2) {
  __shared__ u16b As[BM * BK];
  __shared__ u16b Bs[BN * BK];
  const int tid = threadIdx.x;
  const int nbx = gridDim.x;
  const int id = xcd_swz(blockIdx.y * nbx + blockIdx.x, nbx * gridDim.y);
  const int n0 = (id % nbx) * BN;
  const int m0 = (id / nbx) * BM;
  const int hi = (m0 >= Mhalf);
  const u16b* B = hi ? B2 : B1;
  u16b* C = hi ? C2 : C1;
  const u16b* bias = hi ? bias2 : bias1;
  float* aux = hi ? aux2 : aux1;
  const int ldc = hi ? ldc2 : ldc1;
  const int mloc = m0 - (hi ? Mhalf : 0);
  const int wave = tid >> 6, lane = tid & 63;
  const int wm = (wave >> 1) * 64, wn = (wave & 1) * 64;
  const int lr = lane & 15, lg = lane >> 4;

  f32x4 acc[4][4] = {};

  for (int k0 = 0; k0 < K; k0 += BK) {
    stage_tile(A + (size_t)m0 * lda + k0, lda, As, wave, lane);
    stage_tile(B + (size_t)n0 * ldb + k0, ldb, Bs, wave, lane);
    __syncthreads();
#pragma unroll
    for (int kk = 0; kk < BK; kk += 32) {
      short8 afr[4], bfr[4];
#pragma unroll
      for (int i = 0; i < 4; ++i) {
        int r = wm + i * 16 + lr;
        afr[i] = *(const short8*)&As[r * 64 + (((kk >> 3) + lg) ^ (r & 7)) * 8];
      }
#pragma unroll
      for (int j = 0; j < 4; ++j) {
        int r = wn + j * 16 + lr;
        bfr[j] = *(const short8*)&Bs[r * 64 + (((kk >> 3) + lg) ^ (r & 7)) * 8];
      }
#pragma unroll
      for (int i = 0; i < 4; ++i)
#pragma unroll
        for (int j = 0; j < 4; ++j)
          acc[i][j] = __builtin_amdgcn_mfma_f32_16x16x32_bf16(
              afr[i], bfr[j], acc[i][j], 0, 0, 0);
    }
    __syncthreads();
  }

#pragma unroll
  for (int i = 0; i < 4; ++i) {
    int rbase = mloc + wm + i * 16 + lg * 4;
#pragma unroll
    for (int j = 0; j < 4; ++j) {
      int col = n0 + wn + j * 16 + lr;
      if (col < N) {
        float bv = (EPI == 1) ? b2f(bias[col]) : 0.f;
#pragma unroll
        for (int e = 0; e < 4; ++e) {
          float v = acc[i][j][e];
          if (EPI == 1) v = softplus_fast(v + bv);
          C[(size_t)(rbase + e) * ldc + col] = f2b(v);
          if (EPI == 2 && col >= 64)
            aux[(size_t)(rbase + e) * 32 + (col - 64)] = v;
        }
      }
    }
  }
}

// ---------------- x_dbl GEMM, split-K=2, f32 partials ----------------------
__global__ __launch_bounds__(256) void gemm2s_kernel(
    const u16b* __restrict__ A, const u16b* __restrict__ B1,
    const u16b* __restrict__ B2, float* __restrict__ P,
    int Mhalf, int Ksplit, int lda, int ldb) {
  __shared__ u16b As[BM * BK];
  __shared__ u16b Bs[BN * BK];
  const int tid = threadIdx.x;
  const int ks = blockIdx.x;
  const int m0 = blockIdx.y * BM;
  const int hi = (m0 >= Mhalf);
  const u16b* B = hi ? B2 : B1;
  const int wave = tid >> 6, lane = tid & 63;
  const int wm = (wave >> 1) * 64, wn = (wave & 1) * 64;
  const int lr = lane & 15, lg = lane >> 4;

  f32x4 acc[4][4] = {};

  const int kbeg = ks * Ksplit;
  for (int k0 = kbeg; k0 < kbeg + Ksplit; k0 += BK) {
    stage_tile(A + (size_t)m0 * lda + k0, lda, As, wave, lane);
    stage_tile(B + k0, ldb, Bs, wave, lane);
    __syncthreads();
#pragma unroll
    for (int kk = 0; kk < BK; kk += 32) {
      short8 afr[4], bfr[4];
#pragma unroll
      for (int i = 0; i < 4; ++i) {
        int r = wm + i * 16 + lr;
        afr[i] = *(const short8*)&As[r * 64 + (((kk >> 3) + lg) ^ (r & 7)) * 8];
      }
#pragma unroll
      for (int j = 0; j < 4; ++j) {
        int r = wn + j * 16 + lr;
        bfr[j] = *(const short8*)&Bs[r * 64 + (((kk >> 3) + lg) ^ (r & 7)) * 8];
      }
#pragma unroll
      for (int i = 0; i < 4; ++i)
#pragma unroll
        for (int j = 0; j < 4; ++j)
          acc[i][j] = __builtin_amdgcn_mfma_f32_16x16x32_bf16(
              afr[i], bfr[j], acc[i][j], 0, 0, 0);
    }
    __syncthreads();
  }

  float* Pk = P + (size_t)ks * ((size_t)2 * Mhalf) * 128;
#pragma unroll
  for (int i = 0; i < 4; ++i) {
    int rg = m0 + wm + i * 16 + lg * 4;
#pragma unroll
    for (int j = 0; j < 4; ++j) {
      int col = wn + j * 16 + lr;
#pragma unroll
      for (int e = 0; e < 4; ++e)
        Pk[(size_t)(rg + e) * 128 + col] = acc[i][j][e];
    }
  }
}

__global__ __launch_bounds__(256) void xdbl_reduce_kernel(
    const float* __restrict__ P, u16b* __restrict__ xdf,
    u16b* __restrict__ xdb, float* __restrict__ bcf,
    float* __restrict__ bcb) {
  int e = blockIdx.x * 256 + threadIdx.x;   // over 16384*128
  int col = e & 127;
  int m = e >> 7;
  if (col >= 96) return;
  float v = P[(size_t)e] + P[(size_t)e + (size_t)16384 * 128];
  int hi = (m >= MROWS);
  int mloc = m - (hi ? MROWS : 0);
  u16b* C = hi ? xdb : xdf;
  C[(size_t)mloc * 96 + col] = f2b(v);
  if (col >= 64) {
    float* aux = hi ? bcb : bcf;
    aux[(size_t)mloc * 32 + (col - 64)] = v;
  }
}

// ---------------- Dual depthwise causal conv + SiLU ------------------------
__global__ __launch_bounds__(256) void conv_kernel(
    const u16b* __restrict__ xz, const u16b* __restrict__ cwf,
    const u16b* __restrict__ cbf, const u16b* __restrict__ cwb,
    const u16b* __restrict__ cbb, u16b* __restrict__ u_f,
    u16b* __restrict__ u_b) {
  int gid = blockIdx.x * 256 + threadIdx.x;
  int d = gid & (DI - 1);
  int m = gid >> 11;
  int b = m >> 11;
  int l = m & (LSEQ - 1);
  const u16b* xcol = xz + ((size_t)b * LSEQ) * (2 * DI) + d;
  float xv[7];
#pragma unroll
  for (int t = 0; t < 7; ++t) {
    int ll = l + t - 3;
    xv[t] = (ll >= 0 && ll < LSEQ) ? b2f(xcol[(size_t)ll * (2 * DI)]) : 0.f;
  }
  float af = b2f(cbf[d]);
#pragma unroll
  for (int k = 0; k < 4; ++k) af = fmaf(b2f(cwf[d * 4 + k]), xv[k], af);
  float ab = b2f(cbb[d]);
#pragma unroll
  for (int j = 0; j < 4; ++j) ab = fmaf(b2f(cwb[d * 4 + 3 - j]), xv[3 + j], ab);
  float sf = af * fast_rcp(1.f + __expf(-af));
  float sb = ab * fast_rcp(1.f + __expf(-ab));
  u_f[(size_t)m * DI + d] = f2b(sf);
  u_b[((size_t)b * LSEQ + (LSEQ - 1 - l)) * DI + d] = f2b(sb);
}

// ---------------- Chunked selective scan ----------------------------------
__device__ __forceinline__ bool detect_intA(const u16b* alog, int d, float* An2) {
  bool fast = true;
#pragma unroll
  for (int n = 0; n < DS; ++n) {
    float a = __expf(b2f(alog[d * DS + n]));
    An2[n] = -a * 1.44269504088896f;
    fast = fast && (fabsf(a - (float)(n + 1)) < 0.02f * (float)(n + 1));
  }
  return fast;
}

#define CHUNK_BODY_FAST() do {                                        \
    float du = cd * cu; s += cd;                                      \
    float dA[DS]; pow_ladder(__expf(-cd), dA);                        \
    _Pragma("unroll") for (int n = 0; n < DS; ++n)                    \
      h[n] = fmaf(dA[n], h[n], du * bl[n]);                           \
    bl += 32;                                                         \
  } while (0)

#define CHUNK_BODY_SLOW() do {                                        \
    float du = cd * cu; s += cd;                                      \
    _Pragma("unroll") for (int n = 0; n < DS; ++n) {                  \
      float dA = exp2f(cd * An2[n]);                                  \
      h[n] = fmaf(dA, h[n], du * bl[n]);                              \
    }                                                                 \
    bl += 32;                                                         \
  } while (0)

__global__ __launch_bounds__(256) void scan_chunk_kernel(
    const u16b* __restrict__ xz, const u16b* __restrict__ u_f,
    const u16b* __restrict__ u_b, const u16b* __restrict__ dltb,
    const float* __restrict__ bc_f, const float* __restrict__ bc_b,
    const u16b* __restrict__ alog_f, const u16b* __restrict__ alog_b,
    float* __restrict__ hstate, float* __restrict__ sdelta) {
  int bx = blockIdx.x;
  int dblk = bx & 7;
  int chunk = (bx >> 3) & 31;
  // Chunk 31's local h and sdelta only feed carry's DISCARDED final update;
  // skip the whole block (carry is guarded to never read this slot).
  if (chunk == NCH - 1) return;
  int b = (bx >> 8) & 3;
  int dir = bx >> 10;
  int d = dblk * 256 + threadIdx.x;

  const u16b* uptr = dir ? u_b : u_f;
  const u16b* dlt = dir ? dltb : xz;
  const int ldd = dir ? DI : 2 * DI;
  const float* bcp = dir ? bc_b : bc_f;
  const u16b* alog = dir ? alog_b : alog_f;

  const size_t mb = (size_t)b * LSEQ + (size_t)chunk * CLEN;
  const float* bl = bcp + mb * 32;
  float An2[DS];
  bool fastA = detect_intA(alog, d, An2);

  float h[DS];
#pragma unroll
  for (int n = 0; n < DS; ++n) h[n] = 0.f;
  float s = 0.f;
  unsigned od = (unsigned)mb * (unsigned)ldd + (unsigned)d;
  unsigned ou = (unsigned)mb * DI + (unsigned)d;
  float nd = b2f(dlt[od]);
  float nu = b2f(uptr[ou]);
  float cd, cu;
  if (fastA) {
#pragma unroll 4
    for (int l = 0; l < CLEN - 1; ++l) {
      cd = nd; cu = nu;
      od += ldd; ou += DI;
      nd = b2f(dlt[od]); nu = b2f(uptr[ou]);
      CHUNK_BODY_FAST();
    }
    cd = nd; cu = nu;
    CHUNK_BODY_FAST();
  } else {
#pragma unroll 4
    for (int l = 0; l < CLEN - 1; ++l) {
      cd = nd; cu = nu;
      od += ldd; ou += DI;
      nd = b2f(dlt[od]); nu = b2f(uptr[ou]);
      CHUNK_BODY_SLOW();
    }
    cd = nd; cu = nu;
    CHUNK_BODY_SLOW();
  }
  size_t slot = (size_t)((dir * 4 + b) * 32 + chunk) * 2048 + d;
  float* hp = hstate + slot * 16;
#pragma unroll
  for (int i = 0; i < 4; ++i)
    ((f32x4*)hp)[i] = *(f32x4*)&h[i * 4];
  sdelta[slot] = s;
}

// Carry: one thread per (dir,b,d,n) = 262144 threads (1024 blocks).
// Guarded: never reads chunk 31's (unwritten) local h / sdelta.
__global__ __launch_bounds__(256) void scan_carry_kernel(
    const u16b* __restrict__ alog_f, const u16b* __restrict__ alog_b,
    float* __restrict__ hstate, const float* __restrict__ sdelta) {
  int gid = blockIdx.x * 256 + threadIdx.x;
  int n = gid & (DS - 1);
  int d = (gid >> 4) & (DI - 1);
  int b = (gid >> 15) & 3;
  int dir = gid >> 17;
  const u16b* alog = dir ? alog_b : alog_f;
  float An2 = -__expf(b2f(alog[d * DS + n])) * 1.44269504088896f;
  float h = 0.f;
  size_t base = (size_t)((dir * 4 + b) * 32) * 2048 + d;
  for (int c = 0; c < NCH; ++c) {
    size_t slot = base + (size_t)c * 2048;
    float* hp = hstate + slot * 16 + n;
    float hw = h;   // carry-in state for chunk c
    if (c + 1 < NCH) {
      float hl = *hp;
      float sdv = sdelta[slot];
      float P = exp2f(An2 * sdv);
      h = fmaf(P, h, hl);
    }
    *hp = hw;
  }
}

#define APPLY_BODY_FAST() do {                                        \
    float du = cd * cu;                                               \
    float dA[DS]; pow_ladder(__expf(-cd), dA);                        \
    float y0 = 0.f, y1 = 0.f;                                         \
    _Pragma("unroll") for (int n = 0; n < DS; n += 2) {               \
      h[n] = fmaf(dA[n], h[n], du * bl[n]);                           \
      y0 = fmaf(h[n], bl[16 + n], y0);                                \
      h[n + 1] = fmaf(dA[n + 1], h[n + 1], du * bl[n + 1]);           \
      y1 = fmaf(h[n + 1], bl[17 + n], y1);                            \
    }                                                                 \
    float sz = cz * fast_rcp(1.f + __expf(-cz));                      \
    float out = (y0 + y1 + Dd * cu) * sz;                             \
    uptr[oo] = f2b_cvt(out); oo += DI; bl += 32;                      \
  } while (0)

#define APPLY_BODY_SLOW() do {                                        \
    float du = cd * cu;                                               \
    float y = 0.f;                                                    \
    _Pragma("unroll") for (int n = 0; n < DS; ++n) {                  \
      float dA = exp2f(cd * An2[n]);                                  \
      h[n] = fmaf(dA, h[n], du * bl[n]);                              \
      y = fmaf(h[n], bl[16 + n], y);                                  \
    }                                                                 \
    float sz = cz * fast_rcp(1.f + __expf(-cz));                      \
    float out = (y + Dd * cu) * sz;                                   \
    uptr[oo] = f2b_cvt(out); oo += DI; bl += 32;                      \
  } while (0)

__global__ __launch_bounds__(256) void scan_apply_kernel(
    const u16b* __restrict__ xz, u16b* __restrict__ u_f,
    u16b* __restrict__ u_b, const u16b* __restrict__ dltb,
    const float* __restrict__ bc_f, const float* __restrict__ bc_b,
    const u16b* __restrict__ alog_f, const u16b* __restrict__ alog_b,
    const u16b* __restrict__ dv_f, const u16b* __restrict__ dv_b,
    const float* __restrict__ hstate) {
  int bx = blockIdx.x;
  int dblk = bx & 7;
  int chunk = (bx >> 3) & 31;
  int b = (bx >> 8) & 3;
  int dir = bx >> 10;
  int d = dblk * 256 + threadIdx.x;

  u16b* uptr = dir ? u_b : u_f;
  const u16b* dlt = dir ? dltb : xz;
  const int ldd = dir ? DI : 2 * DI;
  const float* bcp = dir ? bc_b : bc_f;
  const u16b* alog = dir ? alog_b : alog_f;
  const u16b* dv = dir ? dv_b : dv_f;

  const size_t mb0 = (size_t)b * LSEQ;
  const size_t mb = mb0 + (size_t)chunk * CLEN;
  const float* bl = bcp + mb * 32;
  float An2[DS];
  bool fastA = detect_intA(alog, d, An2);
  float Dd = b2f(dv[d]);
  float h[DS];
  {
    size_t slot = (size_t)((dir * 4 + b) * 32 + chunk) * 2048 + d;
    const float* hp = hstate + slot * 16;
#pragma unroll
    for (int i = 0; i < 4; ++i)
      *(f32x4*)&h[i * 4] = ((const f32x4*)hp)[i];
  }

  size_t zs0 = dir ? (mb0 + (LSEQ - 1 - (size_t)chunk * CLEN)) : mb;
  const int zst = dir ? -(2 * DI) : (2 * DI);
  unsigned od = (unsigned)mb * (unsigned)ldd + (unsigned)d;
  unsigned ou = (unsigned)mb * DI + (unsigned)d;
  unsigned oo = ou;
  int oz = (int)zs0 * (2 * DI) + DI + d;
  float nd = b2f(dlt[od]);
  float nu = b2f(uptr[ou]);
  float nz = b2f(xz[oz]);
  float cd, cu, cz;
  if (fastA) {
#pragma unroll 4
    for (int l = 0; l < CLEN - 1; ++l) {
      cd = nd; cu = nu; cz = nz;
      od += ldd; ou += DI; oz += zst;
      nd = b2f(dlt[od]); nu = b2f(uptr[ou]); nz = b2f(xz[oz]);
      APPLY_BODY_FAST();
    }
    cd = nd; cu = nu; cz = nz;
    APPLY_BODY_FAST();
  } else {
#pragma unroll 4
    for (int l = 0; l < CLEN - 1; ++l) {
      cd = nd; cu = nu; cz = nz;
      od += ldd; ou += DI; oz += zst;
      nd = b2f(dlt[od]); nu = b2f(uptr[ou]); nz = b2f(xz[oz]);
      APPLY_BODY_SLOW();
    }
    cd = nd; cu = nu; cz = nz;
    APPLY_BODY_SLOW();
  }
}

// ---------------- Combine: yc[m] = (y_f[m] + y_b[rev(m)]) / 2 --------------
__global__ __launch_bounds__(256) void combine_kernel(
    const u16b* __restrict__ yf, const u16b* __restrict__ yb_rev,
    u16b* __restrict__ yc) {
  size_t i = ((size_t)blockIdx.x * 256 + threadIdx.x) * 8;
  size_t m = i >> 11;
  size_t dcol = i & (DI - 1);
  size_t mr = m ^ (LSEQ - 1);
  uint4 a = *(const uint4*)(yf + m * DI + dcol);
  uint4 b = *(const uint4*)(yb_rev + mr * DI + dcol);
  const u16b* ap = (const u16b*)&a;
  const u16b* bp = (const u16b*)&b;
  uint4 o;
  u16b* op = (u16b*)&o;
#pragma unroll
  for (int j = 0; j < 8; ++j) op[j] = f2b(0.5f * (b2f(ap[j]) + b2f(bp[j])));
  *(uint4*)(yc + i) = o;
}

extern "C" void kernel_launch(void* const* d_in, const int* in_sizes, int n_in,
                              void* d_out, int out_size, void* d_ws,
                              size_t ws_size, hipStream_t stream) {
  char* ws = (char*)d_ws;
  u16b* xz    = (u16b*)(ws);
  u16b* u_f   = (u16b*)(ws + 67108864);
  u16b* u_b   = (u16b*)(ws + 100663296);
  u16b* arena = (u16b*)(ws + 134217728);
  u16b* xdf   = (u16b*)(ws + 167772160);
  u16b* xdb   = (u16b*)(ws + 169345024);
  float* bcf  = (float*)(ws + 170917888);
  float* bcb  = (float*)(ws + 171966464);
  u16b* opw_c  = (u16b*)(ws + 173015040);   // 4 MiB
  u16b* xpwf_c = (u16b*)(ws + 177209344);
  u16b* xpwb_c = (u16b*)(ws + 177602560);
  u16b* dpwf_c = (u16b*)(ws + 177995776);
  u16b* dpwb_c = (u16b*)(ws + 178257920);
  u16b* cwf_c  = (u16b*)(ws + 178520064);
  u16b* cwb_c  = (u16b*)(ws + 178536448);
  u16b* cbf_c  = (u16b*)(ws + 178552832);
  u16b* cbb_c  = (u16b*)(ws + 178556928);
  u16b* dpbf_c = (u16b*)(ws + 178561024);
  u16b* dpbb_c = (u16b*)(ws + 178565120);
  u16b* alf_c  = (u16b*)(ws + 178569216);
  u16b* alb_c  = (u16b*)(ws + 178634752);
  u16b* dvf_c  = (u16b*)(ws + 178700288);
  u16b* dvb_c  = (u16b*)(ws + 178704384);
  int*  flag   = (int*)(ws + 178708480);
  float* hstate = (float*)(ws + 178712576); // 32 MiB
  float* sdelta = (float*)(ws + 212267008); // 2 MiB -> end 214,364,160

  u16b* hs_c  = arena;           // 16 MiB, dead after in-proj GEMM
  u16b* inw_c = arena + 8388608; // 8 MiB, dead after in-proj GEMM
  float* Pbuf = (float*)arena;   // 16.8 MiB, live gemm2s..reduce only
  u16b* dltb  = arena;           // live dt-GEMM..scan
  u16b* y_c   = arena;           // live combine..out-proj

  dim3 blk(256);
  // 0) sniff dtype; canonicalize ALL inputs to bf16 in ONE launch
  sniff_kernel<<<dim3(1), dim3(64), 0, stream>>>((const unsigned int*)d_in[0], flag);
  ConvTab ct = {{d_in[0], d_in[1], d_in[16],
                 d_in[2], d_in[3], d_in[4], d_in[5], d_in[6], d_in[7], d_in[8],
                 d_in[9], d_in[10], d_in[11], d_in[12], d_in[13], d_in[14],
                 d_in[15]},
                {hs_c, inw_c, opw_c,
                 cwf_c, cbf_c, cwb_c, cbb_c, xpwf_c, dpwf_c, dpbf_c, xpwb_c,
                 dpwb_c, dpbb_c, alf_c, alb_c, dvf_c, dvb_c}};
  convert_all_kernel<<<dim3(7534), blk, 0, stream>>>(ct, flag);

  // 1) xz = hs @ in_proj_w^T  (256^2 8-phase, R4 schedule)
  gemm8_kernel<<<dim3(16, 32), dim3(512), 0, stream>>>(hs_c, inw_c, xz,
      MROWS, 2 * DI, DM, DM, DM, 2 * DI);
  // 2) conv both dirs
  conv_kernel<<<dim3(65536), blk, 0, stream>>>(xz, cwf_c, cbf_c, cwb_c, cbb_c,
                                               u_f, u_b);
  // 3) x_dbl both dirs: split-K=2 into f32 partials (arena), then reduce
  gemm2s_kernel<<<dim3(2, 128), blk, 0, stream>>>(u_f, xpwf_c, xpwb_c, Pbuf,
      MROWS, 1024, DI, DI);
  xdbl_reduce_kernel<<<dim3(8192), blk, 0, stream>>>(Pbuf, xdf, xdb, bcf, bcb);
  // 4) delta both dirs, one launch; fwd C -> xz x-half (ldc=4096)
  gemm2_kernel<1><<<dim3(16, 128), blk, 0, stream>>>(xdf, dpwf_c, dpwb_c,
      xz, dltb, dpbf_c, dpbb_c, nullptr, nullptr, MROWS, DI, 64, 96, 64,
      2 * DI, DI);
  // 5) chunked scan: pass1 -> carry -> pass2
  scan_chunk_kernel<<<dim3(2048), blk, 0, stream>>>(xz, u_f, u_b, dltb, bcf,
      bcb, alf_c, alb_c, hstate, sdelta);
  scan_carry_kernel<<<dim3(1024), blk, 0, stream>>>(alf_c, alb_c, hstate, sdelta);
  scan_apply_kernel<<<dim3(2048), blk, 0, stream>>>(xz, u_f, u_b, dltb, bcf,
      bcb, alf_c, alb_c, dvf_c, dvb_c, hstate);
  // 6) combine -> y_c
  combine_kernel<<<dim3(8192), blk, 0, stream>>>(u_f, u_b, y_c);
  // 7) out = y @ out_proj_w^T -> d_out (dtype per flag)
  gemm_kernel<3><<<dim3(8, 64), blk, 0, stream>>>(y_c, opw_c, d_out, flag,
      MROWS, DM, DI, DI, DI, DM);
}